// Round 6
// baseline (125.666 us; speedup 1.0000x reference)
//
#include <hip/hip_runtime.h>
#include <math.h>

#define LSEQ 512
#define NA 20
#define NCH 8
#define NBLK_IMP 129  // 129*4 = 516 >= 512 impulse waves
#define NBLK_PRE (NBLK_IMP + 1)

// ---------------------------------------------------------------------------
// prep_kernel (grid = 130 + B):
//   blocks 0..128  : impulse responses Wf[c][s] = pyramid(e_s)[c], 4 per block
//                    (verified R0/R1/R4/R5 pyramid code)
//   block 129      : vtn (grid-stride over 400)
//   blocks 130..   : idx extraction for b = blockIdx-130 (HBM-bound x scan)
//   The idx blocks have no dependency on wf/vtn -> they overlap the impulse
//   compute on other CUs within this single launch.
// ---------------------------------------------------------------------------
__global__ __launch_bounds__(256) void prep_kernel(
    const float* __restrict__ x,    // [B,L,A]
    const float* __restrict__ w0,   // [8*3]
    const float* __restrict__ wsg,  // [8*8*8*3]
    const float* __restrict__ lpm,
    const float* __restrict__ pm,
    float* __restrict__ wf,         // [8*512]
    float* __restrict__ vtn,        // [400]
    unsigned char* __restrict__ g_idx) // [B*512]
{
    if (blockIdx.x >= NBLK_PRE) {
        // ---- idx extraction ----
        const int b = blockIdx.x - NBLK_PRE;
        const int t = threadIdx.x;
        const float4* xb = (const float4*)(x + (size_t)b * LSEQ * NA);
        unsigned short pack = 0;
#pragma unroll
        for (int half = 0; half < 2; ++half) {
            const int s = 2 * t + half;
            int id = 255;
#pragma unroll
            for (int q = 0; q < 5; ++q) {
                float4 v = xb[s * 5 + q];
                if (v.x > .5f) id = 4 * q + 0;
                if (v.y > .5f) id = 4 * q + 1;
                if (v.z > .5f) id = 4 * q + 2;
                if (v.w > .5f) id = 4 * q + 3;
            }
            pack |= (unsigned short)(id & 0xFF) << (8 * half);
        }
        ((unsigned short*)(g_idx + (size_t)b * LSEQ))[t] = pack;
        return;
    }

    if (blockIdx.x == NBLK_IMP) {
        for (int o = threadIdx.x; o < NA * NA; o += 256) {
            int j = o / NA, a = o % NA;
            float v = 0.f;
            if (a > j && a <= NA - 2)
                v += fminf(fmaxf(lpm[j * NA + a], 0.001f), 1.0f) * pm[j * NA + a];
            if (a < j)
                v += fminf(fmaxf(lpm[a * NA + j], 0.001f), 1.0f) * pm[a * NA + j];
            vtn[o] = v;
        }
        return;
    }

    // ---- impulse pyramid ----
    const int w = threadIdx.x >> 6;   // wave 0..3 -> impulse index
    const int t = threadIdx.x & 63;   // lane
    const int s = blockIdx.x * 4 + w; // impulse position (>=512: compute, skip write)

    __shared__ float s_h[4][LSEQ];
    __shared__ float s_a[4][NCH * 256];
    __shared__ float s_b[4][NCH * 128];
    float* hh = s_h[w];
    float* aa = s_a[w];
    float* bb = s_b[w];

    for (int i = t; i < LSEQ; i += 64) hh[i] = (i == s) ? 1.f : 0.f;
    __syncthreads();

    const int c = t >> 3;
    const int pb = t & 7;

    {
        float q0 = w0[c * 3 + 0], q1 = w0[c * 3 + 1], q2 = w0[c * 3 + 2];
        float wa = q0, wb = q0 + q1, wc2 = q1 + q2, wd = q2;
        for (int p = pb; p < 256; p += 8) {
            int xx = 2 * p;
            float x0 = (xx > 0) ? hh[xx - 1] : 0.f;
            float x1 = hh[xx];
            float x2 = hh[xx + 1];
            float x3 = (xx + 2 < LSEQ) ? hh[xx + 2] : 0.f;
            aa[c * 256 + p] = 0.5f * (wa * x0 + wb * x1 + wc2 * x2 + wd * x3);
        }
    }
    __syncthreads();

    int Lin = 256;
    for (int li = 0; li < 8; ++li) {
        const float* fin = (li & 1) ? bb : aa;
        float* fout = (li & 1) ? aa : bb;
        const int Lout = Lin >> 1;

        float wa[8], wb[8], wc2[8], wd[8];
        const float* wl = wsg + li * 192 + c * 24;
#pragma unroll
        for (int ci = 0; ci < 8; ++ci) {
            float q0 = wl[ci * 3 + 0], q1 = wl[ci * 3 + 1], q2 = wl[ci * 3 + 2];
            wa[ci] = q0; wb[ci] = q0 + q1; wc2[ci] = q1 + q2; wd[ci] = q2;
        }

        for (int p = pb; p < Lout; p += 8) {
            int xx = 2 * p;
            float acc = 0.f;
#pragma unroll
            for (int ci = 0; ci < 8; ++ci) {
                const float* ip = fin + ci * Lin + xx;
                float x0 = (xx > 0) ? ip[-1] : 0.f;
                float x1 = ip[0];
                float x2 = ip[1];
                float x3 = (xx + 2 < Lin) ? ip[2] : 0.f;
                acc += wa[ci] * x0 + wb[ci] * x1 + wc2[ci] * x2 + wd[ci] * x3;
            }
            fout[c * Lout + p] = 0.5f * acc;
        }
        __syncthreads();
        Lin = Lout;
    }

    if (t < NCH && s < LSEQ) wf[t * 512 + s] = aa[t];
}

// ---------------------------------------------------------------------------
// dot_kernel: one block per b. No x access (idx precomputed), no atomics.
//  thread map: cpair = t&3 (channels 2*cpair, 2*cpair+1), sge = t>>2 (0..63,
//  owns s = sge*4 + 256k, k=0,1).
//  phase 0: Wf strips -> regs (4 float4), vtn + idx -> LDS
//  phase 1: dense h build (R2/R5-verified; own-column writes, k=3 priority)
//  phase 2: per a: 2 b128 h reads (4-lane broadcast, conflict-free), 16 fma,
//           4-level shfl reduce over sge-within-wave, cross-wave add via LDS
// ---------------------------------------------------------------------------
__global__ __launch_bounds__(256) void dot_kernel(
    const unsigned char* __restrict__ g_idx,  // [B*512]
    const float* __restrict__ vtn,    // [400]
    const float* __restrict__ g_std,  // [1]
    const float* __restrict__ wf,     // [8*512]
    float* __restrict__ out)          // [B*160]
{
    const int b = blockIdx.x;
    const int t = threadIdx.x;
    const int cpair = t & 3;
    const int sge = t >> 2;          // 0..63
    const int w = t >> 6;
    const int lane = t & 63;

    __shared__ __align__(16) float s_h[NA * 512];   // 40960B
    __shared__ __align__(16) float s_vtn[NA * NA];  // 1600B
    __shared__ float s_part[4 * NA * NCH];          // 2560B
    __shared__ unsigned char s_idx[LSEQ];           // 512B

    // ---- phase 0 ----
    const int c0 = 2 * cpair, c1 = c0 + 1;
    float4 wr0[2], wr1[2];
#pragma unroll
    for (int k = 0; k < 2; ++k) {
        wr0[k] = *(const float4*)(wf + c0 * 512 + sge * 4 + 256 * k);
        wr1[k] = *(const float4*)(wf + c1 * 512 + sge * 4 + 256 * k);
    }

    ((unsigned short*)s_idx)[t] = ((const unsigned short*)(g_idx + (size_t)b * LSEQ))[t];
    if (t < NA * NA / 4) ((float4*)s_vtn)[t] = ((const float4*)vtn)[t];
    __syncthreads();

    const float stdv = g_std[0];
    const float inv2s2 = 1.f / (2.f * stdv * stdv);
    const float vks[3] = {__expf(-1.f * inv2s2), __expf(-4.f * inv2s2), __expf(-9.f * inv2s2)};

    // ---- phase 1: dense h build (each lane writes only its own column s) ----
    for (int s = t; s < LSEQ; s += 256) {
        const int ai = s_idx[s];
        const bool valid = ai < NA;
#pragma unroll
        for (int a = 0; a < NA; ++a) {
            float v = valid ? (s_vtn[ai * NA + a] + (a == ai ? 1.f : 0.f)) : 0.f;
            s_h[a * 512 + s] = v;
        }
#pragma unroll
        for (int k = 1; k <= 3; ++k) {
            const float add = vks[k - 1];
            if (s == LSEQ - 1) {
                for (int u = LSEQ - 1 - k; u <= LSEQ - 1; ++u) {
                    int tg = s_idx[u];
                    if (tg < NA)
                        s_h[tg * 512 + s] =
                            (valid ? s_vtn[ai * NA + tg] + (tg == ai ? 1.f : 0.f) : 0.f) + add;
                }
            } else if (s >= k) {
                int tg = s_idx[s - k];
                if (tg < NA)
                    s_h[tg * 512 + s] =
                        (valid ? s_vtn[ai * NA + tg] + (tg == ai ? 1.f : 0.f) : 0.f) + add;
            }
            if (s == 0) {
                for (int u = 0; u <= k; ++u) {
                    int tg = s_idx[u];
                    if (tg < NA)
                        s_h[tg * 512 + s] =
                            (valid ? s_vtn[ai * NA + tg] + (tg == ai ? 1.f : 0.f) : 0.f) + add;
                }
            } else if (s + k < LSEQ) {
                int tg = s_idx[s + k];
                if (tg < NA)
                    s_h[tg * 512 + s] =
                        (valid ? s_vtn[ai * NA + tg] + (tg == ai ? 1.f : 0.f) : 0.f) + add;
            }
        }
    }
    __syncthreads();

    // ---- phase 2: dots, 2 channels per thread ----
#pragma unroll 1
    for (int a = 0; a < NA; ++a) {
        const float* hb = s_h + a * 512 + sge * 4;
        float4 h0 = *(const float4*)(hb);
        float4 h1 = *(const float4*)(hb + 256);
        float a0 = h0.x * wr0[0].x + h0.y * wr0[0].y + h0.z * wr0[0].z + h0.w * wr0[0].w
                 + h1.x * wr0[1].x + h1.y * wr0[1].y + h1.z * wr0[1].z + h1.w * wr0[1].w;
        float a1 = h0.x * wr1[0].x + h0.y * wr1[0].y + h0.z * wr1[0].z + h0.w * wr1[0].w
                 + h1.x * wr1[1].x + h1.y * wr1[1].y + h1.z * wr1[1].z + h1.w * wr1[1].w;
        a0 += __shfl_xor(a0, 4);  a1 += __shfl_xor(a1, 4);
        a0 += __shfl_xor(a0, 8);  a1 += __shfl_xor(a1, 8);
        a0 += __shfl_xor(a0, 16); a1 += __shfl_xor(a1, 16);
        a0 += __shfl_xor(a0, 32); a1 += __shfl_xor(a1, 32);
        if (lane < 4) {
            s_part[w * (NA * NCH) + a * NCH + c0] = a0;
            s_part[w * (NA * NCH) + a * NCH + c1] = a1;
        }
    }
    __syncthreads();

    if (t < NA * NCH)
        out[(size_t)b * (NA * NCH) + t] =
            s_part[t] + s_part[160 + t] + s_part[320 + t] + s_part[480 + t];
}

extern "C" void kernel_launch(void* const* d_in, const int* in_sizes, int n_in,
                              void* d_out, int out_size, void* d_ws, size_t ws_size,
                              hipStream_t stream) {
    const float* x    = (const float*)d_in[0];
    // d_in[1] = masks (bool) — unused; mask derived from x
    const float* lpm  = (const float*)d_in[2];
    const float* pm   = (const float*)d_in[3];
    const float* stdp = (const float*)d_in[4];
    const float* w0   = (const float*)d_in[5];
    const float* wsg  = (const float*)d_in[6];
    float* out = (float*)d_out;

    const int B = in_sizes[0] / (LSEQ * NA);  // 1024

    float* vtn = (float*)d_ws;                         // 400 floats (pad to 1024)
    float* wfb = (float*)d_ws + 1024;                  // 8*512 floats
    unsigned char* g_idx = (unsigned char*)d_ws + (1024 + 8 * 512) * 4;  // B*512 bytes

    prep_kernel<<<dim3(NBLK_PRE + B), dim3(256), 0, stream>>>(x, w0, wsg, lpm, pm, wfb, vtn, g_idx);
    dot_kernel<<<dim3(B), dim3(256), 0, stream>>>(g_idx, vtn, stdp, wfb, out);
}